// Round 1
// baseline (424.534 us; speedup 1.0000x reference)
//
#include <hip/hip_runtime.h>

#define BATCH   1024
#define NNODES  100
#define KDIM    640     // 5*128
#define POOL    128
#define TOPK    4
#define PDIM    2304    // 3*6*128

// d_out layout (floats):
#define BP_OFF  0                               // batched_prompt [B, K, PDIM]
#define RS_OFF  (BATCH * TOPK * PDIM)           // reduce_sim scalar
#define SIM_OFF (RS_OFF + 1)                    // similarity [B, POOL]
#define UC_OFF  (SIM_OFF + BATCH * POOL)        // usage_counts [POOL] (as float)

// ---------------------------------------------------------------------------
// Kernel 1: x_key = mean over nodes, then L2-normalize -> x_norm (ws)
// One block per batch row; 640 threads (10 waves), one dim each, coalesced.
__global__ __launch_bounds__(KDIM) void k_mean_norm(const float* __restrict__ x,
                                                    float* __restrict__ xn) {
    const int b = blockIdx.x;
    const int d = threadIdx.x;
    const float* col = x + (size_t)b * (NNODES * KDIM) + d;
    float s = 0.f;
#pragma unroll 10
    for (int n = 0; n < NNODES; ++n) s += col[(size_t)n * KDIM];
    const float m = s * (1.0f / NNODES);

    // block-wide sum of squares (640 threads = 10 waves)
    float sq = m * m;
#pragma unroll
    for (int off = 32; off; off >>= 1) sq += __shfl_down(sq, off, 64);
    __shared__ float red[16];
    const int wv = d >> 6, ln = d & 63;
    if (ln == 0) red[wv] = sq;
    __syncthreads();
    if (d < 64) {
        float v = (d < 10) ? red[d] : 0.f;
#pragma unroll
        for (int off = 8; off; off >>= 1) v += __shfl_down(v, off, 64);
        if (d == 0) red[0] = v;
    }
    __syncthreads();
    const float r = rsqrtf(fmaxf(red[0], 1e-12f));
    xn[(size_t)b * KDIM + d] = m * r;
}

// ---------------------------------------------------------------------------
// Kernel 2: normalize prompt_key, store transposed kT[d][p]; also zero the
// atomic output regions (reduce_sim + usage_counts) for this call.
__global__ __launch_bounds__(KDIM) void k_keynorm(const float* __restrict__ pk,
                                                  float* __restrict__ kT,
                                                  float* __restrict__ out) {
    const int p = blockIdx.x;
    const int d = threadIdx.x;
    if (p == 0) {
        if (d == 0) out[RS_OFF] = 0.f;
        if (d < POOL) out[UC_OFF + d] = 0.f;
    }
    const float v = pk[(size_t)p * KDIM + d];
    float sq = v * v;
#pragma unroll
    for (int off = 32; off; off >>= 1) sq += __shfl_down(sq, off, 64);
    __shared__ float red[16];
    const int wv = d >> 6, ln = d & 63;
    if (ln == 0) red[wv] = sq;
    __syncthreads();
    if (d < 64) {
        float t = (d < 10) ? red[d] : 0.f;
#pragma unroll
        for (int off = 8; off; off >>= 1) t += __shfl_down(t, off, 64);
        if (d == 0) red[0] = t;
    }
    __syncthreads();
    const float r = rsqrtf(fmaxf(red[0], 1e-12f));
    kT[(size_t)d * POOL + p] = v * r;
}

// ---------------------------------------------------------------------------
// Kernel 3: similarity tile (16 rows x 128 pool) + per-row top-4 +
// reduce_sim / usage atomics. 512 threads: p = t&127, row-group = t>>7 (x4 rows).
#define TB 16
__global__ __launch_bounds__(512) void k_sim_topk(const float* __restrict__ xn,
                                                  const float* __restrict__ kT,
                                                  float* __restrict__ out,
                                                  int* __restrict__ idxw) {
    __shared__ float s_x[TB * KDIM];        // 40 KB
    __shared__ float s_sim[TB][POOL + 1];   // padded: conflict-free row scans
    const int b0 = blockIdx.x * TB;
    const int t  = threadIdx.x;

    for (int i = t; i < TB * KDIM; i += 512) s_x[i] = xn[(size_t)b0 * KDIM + i];
    __syncthreads();

    const int p  = t & (POOL - 1);
    const int rg = t >> 7;                  // 0..3 -> rows rg*4 .. rg*4+3
    float acc0 = 0.f, acc1 = 0.f, acc2 = 0.f, acc3 = 0.f;
    const int rb = rg * 4;
    for (int d = 0; d < KDIM; ++d) {
        const float kv = kT[d * POOL + p];  // coalesced, L2-resident
        acc0 += kv * s_x[(rb + 0) * KDIM + d];   // LDS broadcast
        acc1 += kv * s_x[(rb + 1) * KDIM + d];
        acc2 += kv * s_x[(rb + 2) * KDIM + d];
        acc3 += kv * s_x[(rb + 3) * KDIM + d];
    }
    s_sim[rb + 0][p] = acc0;
    s_sim[rb + 1][p] = acc1;
    s_sim[rb + 2][p] = acc2;
    s_sim[rb + 3][p] = acc3;
    out[SIM_OFF + (size_t)(b0 + rb + 0) * POOL + p] = acc0;
    out[SIM_OFF + (size_t)(b0 + rb + 1) * POOL + p] = acc1;
    out[SIM_OFF + (size_t)(b0 + rb + 2) * POOL + p] = acc2;
    out[SIM_OFF + (size_t)(b0 + rb + 3) * POOL + p] = acc3;
    __syncthreads();

    if (t < TB) {
        // insertion top-4; strict '>' keeps earliest index on ties (lax.top_k)
        float v0 = -1e30f, v1 = -1e30f, v2 = -1e30f, v3 = -1e30f;
        int   i0 = 0, i1 = 0, i2 = 0, i3 = 0;
        for (int pp = 0; pp < POOL; ++pp) {
            const float v = s_sim[t][pp];
            if (v > v3) {
                if (v > v0)      { v3=v2;i3=i2; v2=v1;i2=i1; v1=v0;i1=i0; v0=v;i0=pp; }
                else if (v > v1) { v3=v2;i3=i2; v2=v1;i2=i1; v1=v; i1=pp; }
                else if (v > v2) { v3=v2;i3=i2; v2=v; i2=pp; }
                else             { v3=v; i3=pp; }
            }
        }
        const int b = b0 + t;
        idxw[b * TOPK + 0] = i0;
        idxw[b * TOPK + 1] = i1;
        idxw[b * TOPK + 2] = i2;
        idxw[b * TOPK + 3] = i3;
        atomicAdd(out + RS_OFF, (v0 + v1 + v2 + v3) * (1.0f / BATCH));
        atomicAdd(out + UC_OFF + i0, 1.0f);
        atomicAdd(out + UC_OFF + i1, 1.0f);
        atomicAdd(out + UC_OFF + i2, 1.0f);
        atomicAdd(out + UC_OFF + i3, 1.0f);
    }
}

// ---------------------------------------------------------------------------
// Kernel 4: batched_prompt[b,k,:] = prompt[idx[b,k],:]  (float4 copy)
__global__ __launch_bounds__(256) void k_gather(const float* __restrict__ prompt,
                                                const int* __restrict__ idxw,
                                                float* __restrict__ out) {
    const int bk = blockIdx.x;              // 0 .. B*K-1
    const int j  = idxw[bk];
    const float4* src = (const float4*)(prompt + (size_t)j * PDIM);
    float4* dst = (float4*)(out + BP_OFF + (size_t)bk * PDIM);
#pragma unroll
    for (int i = threadIdx.x; i < PDIM / 4; i += 256) dst[i] = src[i];
}

// ---------------------------------------------------------------------------
extern "C" void kernel_launch(void* const* d_in, const int* in_sizes, int n_in,
                              void* d_out, int out_size, void* d_ws, size_t ws_size,
                              hipStream_t stream) {
    const float* x_embed = (const float*)d_in[0];   // [B, N, KDIM]
    const float* prompt  = (const float*)d_in[1];   // [POOL, 1, PDIM]
    const float* pkey    = (const float*)d_in[2];   // [POOL, KDIM]
    float* out = (float*)d_out;

    float* xn   = (float*)d_ws;                         // B*KDIM
    float* kT   = xn + (size_t)BATCH * KDIM;            // KDIM*POOL
    int*   idxw = (int*)(kT + (size_t)KDIM * POOL);     // B*TOPK

    k_keynorm  <<<POOL,       KDIM, 0, stream>>>(pkey, kT, out);
    k_mean_norm<<<BATCH,      KDIM, 0, stream>>>(x_embed, xn);
    k_sim_topk <<<BATCH / TB, 512,  0, stream>>>(xn, kT, out, idxw);
    k_gather   <<<BATCH*TOPK, 256,  0, stream>>>(prompt, idxw, out);
}

// Round 2
// 393.036 us; speedup vs baseline: 1.0801x; 1.0801x over previous
//
#include <hip/hip_runtime.h>

#define BATCH   1024
#define NNODES  100
#define KDIM    640     // 5*128
#define POOL    128
#define TOPK    4
#define PDIM    2304    // 3*6*128
#define ROWF4   (KDIM / 4)          // 160 float4 per node-row
#define NF4     (NNODES * ROWF4)    // 16000 float4 per batch row

// d_out layout (floats):
#define BP_OFF  0                               // batched_prompt [B, K, PDIM]
#define RS_OFF  (BATCH * TOPK * PDIM)           // reduce_sim scalar
#define SIM_OFF (RS_OFF + 1)                    // similarity [B, POOL]
#define UC_OFF  (SIM_OFF + BATCH * POOL)        // usage_counts [POOL] (as float)

// ---------------------------------------------------------------------------
// Kernel 1: normalize prompt_key, store transposed kT[d][p]; zero the atomic
// output regions (reduce_sim + usage_counts) for this call.
__global__ __launch_bounds__(KDIM) void k_keynorm(const float* __restrict__ pk,
                                                  float* __restrict__ kT,
                                                  float* __restrict__ out) {
    const int p = blockIdx.x;
    const int d = threadIdx.x;
    if (p == 0) {
        if (d == 0) out[RS_OFF] = 0.f;
        if (d < POOL) out[UC_OFF + d] = 0.f;
    }
    const float v = pk[(size_t)p * KDIM + d];
    float sq = v * v;
#pragma unroll
    for (int off = 32; off; off >>= 1) sq += __shfl_down(sq, off, 64);
    __shared__ float red[16];
    const int wv = d >> 6, ln = d & 63;
    if (ln == 0) red[wv] = sq;
    __syncthreads();
    if (d < 64) {
        float t = (d < 10) ? red[d] : 0.f;
#pragma unroll
        for (int off = 8; off; off >>= 1) t += __shfl_down(t, off, 64);
        if (d == 0) red[0] = t;
    }
    __syncthreads();
    const float r = rsqrtf(fmaxf(red[0], 1e-12f));
    kT[(size_t)d * POOL + p] = v * r;   // transposed for coalesced sim reads
}

// ---------------------------------------------------------------------------
// Kernel 2 (fused): one block per batch row b.
//   phase 1: mean over nodes (float4 loads, 16 B/lane)
//   phase 2: similarity vs kT (L2-resident), scaled by rsqrt(sumsq) at the end
//   phase 3: top-4 + reduce_sim / usage atomics
//   phase 4: gather the 4 selected prompts (idx via LDS, no global round-trip)
__global__ __launch_bounds__(KDIM) void k_fused(const float* __restrict__ x,
                                                const float* __restrict__ kT,
                                                const float* __restrict__ prompt,
                                                float* __restrict__ out) {
    __shared__ __align__(16) float s_red[4][ROWF4][4];  // 10 KB; reused as s_p2
    __shared__ __align__(16) float s_xn[KDIM];          // raw mean (unnormalized)
    __shared__ float s_sq[ROWF4];
    __shared__ float s_sim[POOL];
    __shared__ float s_scale;
    __shared__ int   s_idx[TOPK];

    const int b = blockIdx.x;
    const int t = threadIdx.x;

    // ---- phase 1: mean. thread t covers float4-column c = t%160, n = t/160 + 4i
    {
        const float4* row = (const float4*)(x + (size_t)b * (NNODES * KDIM));
        float4 a = make_float4(0.f, 0.f, 0.f, 0.f);
#pragma unroll 5
        for (int i = 0; i < NNODES / 4; ++i) {
            const float4 v = row[t + KDIM * i];          // coalesced 1 KB/wave
            a.x += v.x; a.y += v.y; a.z += v.z; a.w += v.w;
        }
        const int g = t / ROWF4, c = t % ROWF4;
        *(float4*)&s_red[g][c][0] = a;
    }
    __syncthreads();
    if (t < ROWF4) {
        const float4 r0 = *(const float4*)&s_red[0][t][0];
        const float4 r1 = *(const float4*)&s_red[1][t][0];
        const float4 r2 = *(const float4*)&s_red[2][t][0];
        const float4 r3 = *(const float4*)&s_red[3][t][0];
        float4 m;
        m.x = (r0.x + r1.x + r2.x + r3.x) * (1.0f / NNODES);
        m.y = (r0.y + r1.y + r2.y + r3.y) * (1.0f / NNODES);
        m.z = (r0.z + r1.z + r2.z + r3.z) * (1.0f / NNODES);
        m.w = (r0.w + r1.w + r2.w + r3.w) * (1.0f / NNODES);
        *(float4*)&s_xn[t * 4] = m;
        s_sq[t] = m.x * m.x + m.y * m.y + m.z * m.z + m.w * m.w;
    }
    __syncthreads();
    if (t < 64) {
        float v = s_sq[t] + s_sq[t + 64] + ((t < 32) ? s_sq[t + 128] : 0.f);
#pragma unroll
        for (int off = 32; off; off >>= 1) v += __shfl_down(v, off, 64);
        if (t == 0) s_scale = rsqrtf(fmaxf(v, 1e-12f));
    }
    __syncthreads();                    // s_red dead from here; reuse as s_p2

    // ---- phase 2: partial dots. p = t&127, d-stripe g2 = t>>7 (5 stripes of 128)
    float (*s_p2)[POOL] = (float (*)[POOL])&s_red[0][0][0];
    {
        const int p = t & (POOL - 1), g2 = t >> 7;
        const float* kp = kT + (size_t)(g2 * 128) * POOL + p;
        const float* xp = s_xn + g2 * 128;
        float a0 = 0.f, a1 = 0.f;
#pragma unroll 8
        for (int d = 0; d < 128; d += 2) {
            a0 += kp[(d + 0) * POOL] * xp[d + 0];        // kT: 256 B/wave, L2-hot
            a1 += kp[(d + 1) * POOL] * xp[d + 1];        // s_xn: LDS broadcast
        }
        s_p2[g2][p] = a0 + a1;
    }
    __syncthreads();
    if (t < POOL) {
        const float sim = (s_p2[0][t] + s_p2[1][t] + s_p2[2][t] + s_p2[3][t] +
                           s_p2[4][t]) * s_scale;
        out[SIM_OFF + (size_t)b * POOL + t] = sim;
        s_sim[t] = sim;
    }
    __syncthreads();

    // ---- phase 3: top-4 (strict '>' keeps earliest index on ties, lax.top_k)
    if (t == 0) {
        float v0 = -1e30f, v1 = -1e30f, v2 = -1e30f, v3 = -1e30f;
        int   i0 = 0, i1 = 0, i2 = 0, i3 = 0;
        for (int pp = 0; pp < POOL; ++pp) {
            const float v = s_sim[pp];
            if (v > v3) {
                if (v > v0)      { v3=v2;i3=i2; v2=v1;i2=i1; v1=v0;i1=i0; v0=v;i0=pp; }
                else if (v > v1) { v3=v2;i3=i2; v2=v1;i2=i1; v1=v; i1=pp; }
                else if (v > v2) { v3=v2;i3=i2; v2=v; i2=pp; }
                else             { v3=v; i3=pp; }
            }
        }
        s_idx[0] = i0; s_idx[1] = i1; s_idx[2] = i2; s_idx[3] = i3;
        atomicAdd(out + RS_OFF, (v0 + v1 + v2 + v3) * (1.0f / BATCH));
        atomicAdd(out + UC_OFF + i0, 1.0f);
        atomicAdd(out + UC_OFF + i1, 1.0f);
        atomicAdd(out + UC_OFF + i2, 1.0f);
        atomicAdd(out + UC_OFF + i3, 1.0f);
    }
    __syncthreads();

    // ---- phase 4: gather 4 prompts (prompt pool = 1.18 MB, L2-resident)
    if (t < PDIM / 4) {                  // 576 threads, one float4 each
#pragma unroll
        for (int kk = 0; kk < TOPK; ++kk) {
            const float4* src = (const float4*)(prompt + (size_t)s_idx[kk] * PDIM);
            float4* dst = (float4*)(out + BP_OFF + ((size_t)b * TOPK + kk) * PDIM);
            dst[t] = src[t];
        }
    }
}

// ---------------------------------------------------------------------------
extern "C" void kernel_launch(void* const* d_in, const int* in_sizes, int n_in,
                              void* d_out, int out_size, void* d_ws, size_t ws_size,
                              hipStream_t stream) {
    const float* x_embed = (const float*)d_in[0];   // [B, N, KDIM]
    const float* prompt  = (const float*)d_in[1];   // [POOL, 1, PDIM]
    const float* pkey    = (const float*)d_in[2];   // [POOL, KDIM]
    float* out = (float*)d_out;

    float* kT = (float*)d_ws;                       // KDIM * POOL floats

    k_keynorm<<<POOL,  KDIM, 0, stream>>>(pkey, kT, out);
    k_fused  <<<BATCH, KDIM, 0, stream>>>(x_embed, kT, prompt, out);
}

// Round 3
// 356.379 us; speedup vs baseline: 1.1912x; 1.1029x over previous
//
#include <hip/hip_runtime.h>

#define BATCH   1024
#define NNODES  100
#define KDIM    640     // 5*128
#define POOL    128
#define TOPK    4
#define PDIM    2304    // 3*6*128
#define ROWF4   (KDIM / 4)          // 160 float4 per node-row

typedef float v4 __attribute__((ext_vector_type(4)));

// d_out layout (floats):
#define BP_OFF  0                               // batched_prompt [B, K, PDIM]
#define RS_OFF  (BATCH * TOPK * PDIM)           // reduce_sim scalar
#define SIM_OFF (RS_OFF + 1)                    // similarity [B, POOL]
#define UC_OFF  (SIM_OFF + BATCH * POOL)        // usage_counts [POOL] (as float)

// ---------------------------------------------------------------------------
// Kernel 1: normalize prompt_key, store in f4-friendly transposed layout:
//   kT[( (d>>2)*POOL + p )*4 + (d&3)] = key_norm[p][d]
// so the sim kernel can load 4 consecutive d's for pool p as one float4.
// Also zeroes the atomic output regions (reduce_sim + usage_counts).
__global__ __launch_bounds__(KDIM) void k_keynorm(const float* __restrict__ pk,
                                                  float* __restrict__ kT,
                                                  float* __restrict__ out) {
    const int p = blockIdx.x;
    const int d = threadIdx.x;
    if (p == 0) {
        if (d == 0) out[RS_OFF] = 0.f;
        if (d < POOL) out[UC_OFF + d] = 0.f;
    }
    const float v = pk[(size_t)p * KDIM + d];
    float sq = v * v;
#pragma unroll
    for (int off = 32; off; off >>= 1) sq += __shfl_down(sq, off, 64);
    __shared__ float red[16];
    const int wv = d >> 6, ln = d & 63;
    if (ln == 0) red[wv] = sq;
    __syncthreads();
    if (d < 64) {
        float t = (d < 10) ? red[d] : 0.f;
#pragma unroll
        for (int off = 8; off; off >>= 1) t += __shfl_down(t, off, 64);
        if (d == 0) red[0] = t;
    }
    __syncthreads();
    const float r = rsqrtf(fmaxf(red[0], 1e-12f));
    kT[((size_t)(d >> 2) * POOL + p) * 4 + (d & 3)] = v * r;
}

// ---------------------------------------------------------------------------
// Kernel 2 (fused): one block (640 thr = 10 waves) per batch row b.
//   phase 1: mean over nodes (NT float4 loads — x is stream-once)
//   phase 2: sim vs kT (float4 loads, L2-hot), scaled by rsqrt(sumsq)
//   phase 3: wave-parallel top-4 (butterfly argmax x4, lower-idx tie-break)
//   phase 4: gather 4 prompts (L2-hot reads, NT stores)
__global__ __launch_bounds__(KDIM) void k_fused(const float* __restrict__ x,
                                                const float* __restrict__ kT,
                                                const float* __restrict__ prompt,
                                                float* __restrict__ out) {
    __shared__ __align__(16) float s_red[4][ROWF4][4];  // 10 KB; reused as s_p2
    __shared__ __align__(16) float s_xn[KDIM];          // raw mean (unnormalized)
    __shared__ float s_sq[ROWF4];
    __shared__ float s_sim[POOL];
    __shared__ float s_scale;
    __shared__ int   s_idx[TOPK];

    const int b = blockIdx.x;
    const int t = threadIdx.x;

    // ---- phase 1: mean. thread t covers f4-col c = t%160, nodes t/160 + 4i
    {
        const v4* row = (const v4*)(x + (size_t)b * (NNODES * KDIM));
        v4 a = (v4){0.f, 0.f, 0.f, 0.f};
#pragma unroll 5
        for (int i = 0; i < NNODES / 4; ++i) {
            const v4 v = __builtin_nontemporal_load(&row[t + KDIM * i]);
            a += v;
        }
        const int g = t / ROWF4, c = t % ROWF4;
        *(v4*)&s_red[g][c][0] = a;
    }
    __syncthreads();
    if (t < ROWF4) {
        const v4 r0 = *(const v4*)&s_red[0][t][0];
        const v4 r1 = *(const v4*)&s_red[1][t][0];
        const v4 r2 = *(const v4*)&s_red[2][t][0];
        const v4 r3 = *(const v4*)&s_red[3][t][0];
        const v4 m = (r0 + r1 + r2 + r3) * (1.0f / NNODES);
        *(v4*)&s_xn[t * 4] = m;
        s_sq[t] = m.x * m.x + m.y * m.y + m.z * m.z + m.w * m.w;
    }
    __syncthreads();
    if (t < 64) {
        float v = s_sq[t] + s_sq[t + 64] + ((t < 32) ? s_sq[t + 128] : 0.f);
#pragma unroll
        for (int off = 32; off; off >>= 1) v += __shfl_down(v, off, 64);
        if (t == 0) s_scale = rsqrtf(fmaxf(v, 1e-12f));
    }
    __syncthreads();                    // s_red dead from here; reuse as s_p2

    // ---- phase 2: partial dots. p = t&127, d-stripe g2 = t>>7 (5 x 128 dims)
    float (*s_p2)[POOL] = (float (*)[POOL])&s_red[0][0][0];
    {
        const int p = t & (POOL - 1), g2 = t >> 7;
        const v4* kp = (const v4*)kT + (size_t)(g2 * 32) * POOL + p;
        const float* xp = s_xn + g2 * 128;
        float a = 0.f;
#pragma unroll 8
        for (int i = 0; i < 32; ++i) {      // 1 KB/wave-instr, L2-hot
            const v4 kv = kp[(size_t)i * POOL];
            a += kv.x * xp[4*i] + kv.y * xp[4*i+1] + kv.z * xp[4*i+2]
               + kv.w * xp[4*i+3];
        }
        s_p2[g2][p] = a;
    }
    __syncthreads();
    if (t < POOL) {
        const float sim = (s_p2[0][t] + s_p2[1][t] + s_p2[2][t] + s_p2[3][t] +
                           s_p2[4][t]) * s_scale;
        out[SIM_OFF + (size_t)b * POOL + t] = sim;
        s_sim[t] = sim;
    }
    __syncthreads();

    // ---- phase 3: wave-parallel top-4 on wave 0. Tie-break: lower index wins
    // (matches lax.top_k). Butterfly max with (==value -> min index) is
    // associative, so all lanes converge to the global winner each round.
    if (t < 64) {
        float va = s_sim[t], vb = s_sim[t + 64];
        const int ia = t, ib = t + 64;
        float rsum = 0.f;
#pragma unroll
        for (int r = 0; r < TOPK; ++r) {
            float v  = (vb > va) ? vb : va;   // tie -> a (lower index)
            int   ix = (vb > va) ? ib : ia;
#pragma unroll
            for (int off = 32; off; off >>= 1) {
                const float ov = __shfl_xor(v, off, 64);
                const int   oi = __shfl_xor(ix, off, 64);
                if (ov > v || (ov == v && oi < ix)) { v = ov; ix = oi; }
            }
            if (t == 0) { s_idx[r] = ix; rsum += v; }
            if (ix == ia) va = -1e30f;
            else if (ix == ib) vb = -1e30f;
        }
        if (t == 0) {
            atomicAdd(out + RS_OFF, rsum * (1.0f / BATCH));
            atomicAdd(out + UC_OFF + s_idx[0], 1.0f);
            atomicAdd(out + UC_OFF + s_idx[1], 1.0f);
            atomicAdd(out + UC_OFF + s_idx[2], 1.0f);
            atomicAdd(out + UC_OFF + s_idx[3], 1.0f);
        }
    }
    __syncthreads();

    // ---- phase 4: gather 4 prompts (prompt pool 1.18 MB, L2-hot; NT stores)
    if (t < PDIM / 4) {                  // 576 threads, one float4 per k
#pragma unroll
        for (int kk = 0; kk < TOPK; ++kk) {
            const v4* src = (const v4*)(prompt + (size_t)s_idx[kk] * PDIM);
            v4* dst = (v4*)(out + BP_OFF + ((size_t)b * TOPK + kk) * PDIM);
            __builtin_nontemporal_store(src[t], &dst[t]);
        }
    }
}

// ---------------------------------------------------------------------------
extern "C" void kernel_launch(void* const* d_in, const int* in_sizes, int n_in,
                              void* d_out, int out_size, void* d_ws, size_t ws_size,
                              hipStream_t stream) {
    const float* x_embed = (const float*)d_in[0];   // [B, N, KDIM]
    const float* prompt  = (const float*)d_in[1];   // [POOL, 1, PDIM]
    const float* pkey    = (const float*)d_in[2];   // [POOL, KDIM]
    float* out = (float*)d_out;

    float* kT = (float*)d_ws;                       // KDIM * POOL floats

    k_keynorm<<<POOL,  KDIM, 0, stream>>>(pkey, kT, out);
    k_fused  <<<BATCH, KDIM, 0, stream>>>(x_embed, kT, prompt, out);
}